// Round 5
// baseline (1649.082 us; speedup 1.0000x reference)
//
#include <hip/hip_runtime.h>

#define CAPS_EPS 1e-8f

typedef __attribute__((ext_vector_type(8))) short short8;
typedef __attribute__((ext_vector_type(4))) float f32x4;

__device__ inline ushort bf16_rn(float f) {
    uint u = __float_as_uint(f);
    u += 0x7fff + ((u >> 16) & 1);
    return (ushort)(u >> 16);
}
__device__ inline float bf16_f(ushort h) { return __uint_as_float((uint)h << 16); }

// async global->LDS DMA, 16B per lane. LDS dst = wave-uniform base + lane*16.
__device__ __forceinline__ void gld16(const void* g, void* l) {
    __builtin_amdgcn_global_load_lds(
        (const __attribute__((address_space(1))) unsigned int*)g,
        (__attribute__((address_space(3))) unsigned int*)l, 16, 0, 0);
}

// ============================================================
// Layouts:
//   h1hi/h1lo [512][20][20][256] bf16 (NHWC) -- conv1 out, split
//   wBhi/wBlo [256][20736] bf16, k = (ky*9+kx)*256 + c
//   h2  [512*36][256] fp32
//   uT [9216][512]
//   bl  [1152*10][512], Z [10][512], sT [160][512], v [512][160], vT [160][512]
// NOTE: bl/uT/... alias h1 -- they may only be written AFTER conv2 consumed h1.
// ============================================================

// ---------- w2 [256][256*81] -> wB[n][t*256+c] hi/lo ----------
__global__ __launch_bounds__(256) void k_wt2(const float* __restrict__ w2,
                                             ushort* __restrict__ wBhi,
                                             ushort* __restrict__ wBlo) {
    int n = blockIdx.x;
    int c = threadIdx.x;
    const float* src = w2 + (size_t)n * 20736 + c * 81;
    ushort* dh = wBhi + (size_t)n * 20736 + c;
    ushort* dl = wBlo + (size_t)n * 20736 + c;
    for (int t = 0; t < 81; ++t) {
        float f = src[t];
        ushort hi = bf16_rn(f);
        ushort lo = bf16_rn(f - bf16_f(hi));
        dh[t * 256] = hi;
        dl[t * 256] = lo;
    }
}

// ---------- conv1 + relu -> bf16 split NHWC ----------
__global__ __launch_bounds__(256) void k_conv1(const float* __restrict__ x,
                                               const float* __restrict__ w1,
                                               const float* __restrict__ b1,
                                               ushort* __restrict__ h1hi,
                                               ushort* __restrict__ h1lo) {
    int blk = blockIdx.x;
    int b = blk / 5, strip = blk % 5;
    int y0 = strip * 4;
    int c = threadIdx.x;
    float w[81];
#pragma unroll
    for (int k = 0; k < 81; ++k) w[k] = w1[c * 81 + k];
    float bias = b1[c];
    const float* xb = x + (size_t)b * 784;
    for (int dy = 0; dy < 4; ++dy) {
        int y = y0 + dy;
        float acc[20];
#pragma unroll
        for (int i = 0; i < 20; ++i) acc[i] = bias;
#pragma unroll
        for (int ky = 0; ky < 9; ++ky) {
            float xr[28];
            const float4* xp = reinterpret_cast<const float4*>(xb + (y + ky) * 28);
#pragma unroll
            for (int q = 0; q < 7; ++q) {
                float4 v = xp[q];
                xr[q * 4 + 0] = v.x; xr[q * 4 + 1] = v.y;
                xr[q * 4 + 2] = v.z; xr[q * 4 + 3] = v.w;
            }
#pragma unroll
            for (int kx = 0; kx < 9; ++kx) {
                float wv = w[ky * 9 + kx];
#pragma unroll
                for (int xo = 0; xo < 20; ++xo)
                    acc[xo] = fmaf(xr[xo + kx], wv, acc[xo]);
            }
        }
#pragma unroll
        for (int xo = 0; xo < 20; ++xo) {
            float a = fmaxf(acc[xo], 0.f);
            ushort hi = bf16_rn(a);
            ushort lo = bf16_rn(a - bf16_f(hi));
            size_t o = ((size_t)(b * 20 + y) * 20 + xo) * 256 + c;
            h1hi[o] = hi;
            h1lo[o] = lo;
        }
    }
}

// ---------- h2 init with bias (runs BEFORE conv2; touches only h2) ----------
__global__ __launch_bounds__(256) void k_h2init(const float* __restrict__ b2,
                                                float* __restrict__ h2) {
    h2[(size_t)blockIdx.x * 256 + threadIdx.x] = b2[threadIdx.x];
}

// ---------- zero (float4 granularity; runs AFTER conv2 -- bl aliases h1) ----------
__global__ __launch_bounds__(256) void k_zero4(float* __restrict__ p) {
    reinterpret_cast<float4*>(p)[(size_t)blockIdx.x * 256 + threadIdx.x] = make_float4(0, 0, 0, 0);
}

// ---------- conv2: split-bf16 MFMA implicit GEMM, global_load_lds staging ----------
// C[18432][256] += A(im2col h1) * B.  128x128 tile, BK=32, K-split 8.
// 3-term split: hi*hi + hi*lo + lo*hi.  LDS unpadded (DMA is lane-linear).
__global__ __launch_bounds__(256, 4) void k_conv2m(const ushort* __restrict__ h1hi,
                                                   const ushort* __restrict__ h1lo,
                                                   const ushort* __restrict__ wBhi,
                                                   const ushort* __restrict__ wBlo,
                                                   float* __restrict__ h2) {
    __shared__ ushort Ahi[128 * 32];
    __shared__ ushort Alo[128 * 32];
    __shared__ ushort Bhi[128 * 32];
    __shared__ ushort Blo[128 * 32];
    int tid = threadIdx.x;
    int m0 = blockIdx.x * 128;
    int n0 = blockIdx.y * 128;
    int kbase = blockIdx.z * 2592;          // 20736 / 8

    int wv = tid >> 6, lane = tid & 63;

    // ---- DMA mapping: wave wv stages rows [32wv, 32wv+32) of all 4 arrays.
    // instr0: rows 32wv + (lane>>2); instr1: +16.  lane&3 picks 16B chunk.
    int r0 = wv * 32 + (lane >> 2);
    int r1 = r0 + 16;
    int cq = (lane & 3) * 8;                // ushort offset
    int mA0 = m0 + r0, mA1 = m0 + r1;
    int mb0 = mA0 / 36, mp0 = mA0 - mb0 * 36;
    int mb1 = mA1 / 36, mp1 = mA1 - mb1 * 36;
    size_t a0 = ((size_t)mb0 * 400 + (mp0 / 6) * 40 + (mp0 % 6) * 2) * 256 + cq;
    size_t a1 = ((size_t)mb1 * 400 + (mp1 / 6) * 40 + (mp1 % 6) * 2) * 256 + cq;
    size_t b0 = (size_t)(n0 + r0) * 20736 + cq;
    size_t b1 = (size_t)(n0 + r1) * 20736 + cq;
    int ldsw = wv * 1024;                   // ushort offset of this wave's region

    // ---- frag mapping
    int mhalf = (wv >> 1) * 64, nhalf = (wv & 1) * 64;
    int lrow = lane & 15, quad = lane >> 4;

    f32x4 acc[4][4];
#pragma unroll
    for (int a = 0; a < 4; ++a)
#pragma unroll
        for (int bq = 0; bq < 4; ++bq) acc[a][bq] = (f32x4){0.f, 0.f, 0.f, 0.f};

    for (int ks = 0; ks < 81; ++ks) {
        int k = kbase + ks * 32;
        int t = k >> 8, cc = k & 255;
        int ky = t / 9, kx = t - ky * 9;
        size_t koffA = (size_t)(ky * 5120 + kx * 256 + cc);

        __syncthreads();                    // prev iter's reads done
        gld16(h1hi + a0 + koffA, &Ahi[ldsw]);
        gld16(h1hi + a1 + koffA, &Ahi[ldsw + 512]);
        gld16(h1lo + a0 + koffA, &Alo[ldsw]);
        gld16(h1lo + a1 + koffA, &Alo[ldsw + 512]);
        gld16(wBhi + b0 + k, &Bhi[ldsw]);
        gld16(wBhi + b1 + k, &Bhi[ldsw + 512]);
        gld16(wBlo + b0 + k, &Blo[ldsw]);
        gld16(wBlo + b1 + k, &Blo[ldsw + 512]);
        __syncthreads();                    // vmcnt(0) drain -> LDS ready

        short8 bh[4], blo[4];
#pragma unroll
        for (int tn = 0; tn < 4; ++tn) {
            int off = (nhalf + tn * 16 + lrow) * 32 + quad * 8;
            bh[tn] = *reinterpret_cast<short8*>(&Bhi[off]);
            blo[tn] = *reinterpret_cast<short8*>(&Blo[off]);
        }
#pragma unroll
        for (int tm = 0; tm < 4; ++tm) {
            int off = (mhalf + tm * 16 + lrow) * 32 + quad * 8;
            short8 ah = *reinterpret_cast<short8*>(&Ahi[off]);
            short8 al = *reinterpret_cast<short8*>(&Alo[off]);
#pragma unroll
            for (int tn = 0; tn < 4; ++tn) {
                acc[tm][tn] = __builtin_amdgcn_mfma_f32_16x16x32_bf16(ah, bh[tn], acc[tm][tn], 0, 0, 0);
                acc[tm][tn] = __builtin_amdgcn_mfma_f32_16x16x32_bf16(ah, blo[tn], acc[tm][tn], 0, 0, 0);
                acc[tm][tn] = __builtin_amdgcn_mfma_f32_16x16x32_bf16(al, bh[tn], acc[tm][tn], 0, 0, 0);
            }
        }
    }

#pragma unroll
    for (int tm = 0; tm < 4; ++tm) {
        int mrow = m0 + mhalf + tm * 16 + quad * 4;
#pragma unroll
        for (int tn = 0; tn < 4; ++tn) {
            int ncol = n0 + nhalf + tn * 16 + lrow;
#pragma unroll
            for (int r = 0; r < 4; ++r)
                atomicAdd(&h2[(size_t)(mrow + r) * 256 + ncol], acc[tm][tn][r]);
        }
    }
}

// ---------- fused squash + transpose: h2 -> uT[(i*8+n)][b] ----------
__global__ __launch_bounds__(256) void k_squashT(const float* __restrict__ h2,
                                                 float* __restrict__ uT) {
    int i = blockIdx.x;                       // 0..1151
    int b = blockIdx.y * 256 + threadIdx.x;   // 0..511
    int g = i / 36, s = i - g * 36;
    const float* hp = h2 + ((size_t)b * 36 + s) * 256 + g;
    float val[8];
    float s2 = 0.f;
#pragma unroll
    for (int n = 0; n < 8; ++n) {
        val[n] = hp[n * 32];
        s2 = fmaf(val[n], val[n], s2);
    }
    float scale = s2 / ((1.f + s2) * sqrtf(s2 + CAPS_EPS));
#pragma unroll
    for (int n = 0; n < 8; ++n)
        uT[((size_t)i * 8 + n) * 512 + b] = val[n] * scale;
}

// ---------- s[b,j,m] = sum_i c * (W u), c from exp(bl)/Z (or uniform it0) ----------
__global__ __launch_bounds__(256) void k_s(const float* __restrict__ Wc,
                                           const float* __restrict__ uT,
                                           const float* __restrict__ bl,
                                           const float* __restrict__ Z,
                                           float* __restrict__ sT,
                                           int first) {
    __shared__ float lw[8 * 1280];
    int tid = threadIdx.x;
    int i0 = blockIdx.x * 8;
    int b = blockIdx.y * 128 + (tid & 127);
    int mh = tid >> 7;
    const float* wg = Wc + (size_t)i0 * 1280;
#pragma unroll
    for (int r = 0; r < 10; ++r) {
        int q4 = (r * 256 + tid) * 4;
        *reinterpret_cast<float4*>(&lw[q4]) = *reinterpret_cast<const float4*>(wg + q4);
    }
    __syncthreads();
    float rzs[10];
    if (!first) {
#pragma unroll
        for (int j = 0; j < 10; ++j) rzs[j] = 1.0f / Z[j * 512 + b];
    }
    float acc[80];
#pragma unroll
    for (int q = 0; q < 80; ++q) acc[q] = 0.f;
    for (int di = 0; di < 8; ++di) {
        int i = i0 + di;
        float ur[8];
#pragma unroll
        for (int n = 0; n < 8; ++n) ur[n] = uT[((size_t)i * 8 + n) * 512 + b];
#pragma unroll
        for (int j = 0; j < 10; ++j) {
            float c;
            if (first) c = (1.0f / 1152.0f);
            else c = expf(bl[((size_t)i * 10 + j) * 512 + b]) * rzs[j];
            const float* wp = &lw[((di * 10 + j) * 8) * 16 + mh * 8];
#pragma unroll
            for (int mm = 0; mm < 8; ++mm) {
                float uh = 0.f;
#pragma unroll
                for (int n = 0; n < 8; ++n) uh = fmaf(wp[n * 16 + mm], ur[n], uh);
                acc[j * 8 + mm] = fmaf(c, uh, acc[j * 8 + mm]);
            }
        }
    }
#pragma unroll
    for (int j = 0; j < 10; ++j)
#pragma unroll
        for (int mm = 0; mm < 8; ++mm)
            atomicAdd(&sT[(j * 16 + mh * 8 + mm) * 512 + b], acc[j * 8 + mm]);
}

// ---------- v = squash(s); write v, vT; zero sT and Z for next round ----------
__global__ __launch_bounds__(256) void k_v(const float* __restrict__ sT,
                                           float* __restrict__ v,
                                           float* __restrict__ vT,
                                           float* __restrict__ sTz,
                                           float* __restrict__ Z) {
    int idx = blockIdx.x * 256 + threadIdx.x;   // 5120
    int j = idx >> 9;
    int b = idx & 511;
    float sv[16];
    float s2 = 0.f;
#pragma unroll
    for (int m = 0; m < 16; ++m) {
        sv[m] = sT[(j * 16 + m) * 512 + b];
        s2 = fmaf(sv[m], sv[m], s2);
    }
    float scale = s2 / ((1.f + s2) * sqrtf(s2 + CAPS_EPS));
#pragma unroll
    for (int m = 0; m < 16; ++m) {
        float val = sv[m] * scale;
        v[(size_t)b * 160 + j * 16 + m] = val;
        vT[(j * 16 + m) * 512 + b] = val;
        sTz[(j * 16 + m) * 512 + b] = 0.f;
    }
    Z[idx] = 0.f;
}

// ---------- b_log += u . (W v); accumulate Z = sum_i exp(b_log_new) ----------
__global__ __launch_bounds__(256) void k_bupd(const float* __restrict__ Wc,
                                              const float* __restrict__ uT,
                                              const float* __restrict__ vT,
                                              float* __restrict__ bl,
                                              float* __restrict__ Z) {
    __shared__ float lw[8 * 1280];
    int tid = threadIdx.x;
    int i0 = blockIdx.x * 8;
    int b = blockIdx.y * 128 + (tid & 127);
    int ih = tid >> 7;
    const float* wg = Wc + (size_t)i0 * 1280;
#pragma unroll
    for (int r = 0; r < 10; ++r) {
        int q4 = (r * 256 + tid) * 4;
        *reinterpret_cast<float4*>(&lw[q4]) = *reinterpret_cast<const float4*>(wg + q4);
    }
    __syncthreads();
    float ur[4][8];
#pragma unroll
    for (int ii = 0; ii < 4; ++ii) {
        int i = i0 + ih * 4 + ii;
#pragma unroll
        for (int n = 0; n < 8; ++n) ur[ii][n] = uT[((size_t)i * 8 + n) * 512 + b];
    }
    for (int j = 0; j < 10; ++j) {
        float vj[16];
#pragma unroll
        for (int m = 0; m < 16; ++m) vj[m] = vT[(j * 16 + m) * 512 + b];
        float zp = 0.f;
#pragma unroll
        for (int ii = 0; ii < 4; ++ii) {
            int di = ih * 4 + ii;
            const float* wp = &lw[((di * 10 + j) * 8) * 16];
            float t = 0.f;
#pragma unroll
            for (int n = 0; n < 8; ++n) {
                float wvv = 0.f;
#pragma unroll
                for (int m = 0; m < 16; ++m) wvv = fmaf(wp[n * 16 + m], vj[m], wvv);
                t = fmaf(ur[ii][n], wvv, t);
            }
            size_t idx = ((size_t)(i0 + di) * 10 + j) * 512 + b;
            float nb = bl[idx] + t;
            bl[idx] = nb;
            zp += expf(nb);
        }
        atomicAdd(&Z[j * 512 + b], zp);
    }
}

// ---------- caps->out, pred->out, masked dec_in ----------
__global__ __launch_bounds__(256) void k_pred(const float* __restrict__ v,
                                              float* __restrict__ out,
                                              float* __restrict__ dec,
                                              int pred_off) {
    int b = blockIdx.x, t = threadIdx.x;
    __shared__ float sq[160];
    __shared__ float nrm[10];
    __shared__ int ip;
    float val = 0.f;
    if (t < 160) {
        val = v[(size_t)b * 160 + t];
        out[(size_t)b * 160 + t] = val;
        sq[t] = val * val;
    }
    __syncthreads();
    if (t < 10) {
        float s = 0.f;
#pragma unroll
        for (int k = 0; k < 16; ++k) s += sq[t * 16 + k];
        nrm[t] = s;
    }
    __syncthreads();
    if (t == 0) {
        float best = nrm[0];
        int bi = 0;
        for (int j = 1; j < 10; ++j)
            if (nrm[j] > best) { best = nrm[j]; bi = j; }
        ip = bi;
        out[(size_t)pred_off + b] = (float)bi;
    }
    __syncthreads();
    if (t < 160) dec[(size_t)b * 160 + t] = ((t >> 4) == ip) ? val : 0.f;
}

// ---------- decoder GEMM ----------
template <int ACT>
__global__ __launch_bounds__(256) void k_gemm(const float* __restrict__ A,
                                              const float* __restrict__ B,
                                              const float* __restrict__ bias,
                                              float* __restrict__ C,
                                              int M, int K, int N) {
    __shared__ float As[16 * 64];
    __shared__ float Bs[16 * 64];
    int tid = threadIdx.x;
    int m0 = blockIdx.y * 64, n0 = blockIdx.x * 64;
    int arow = tid >> 2, akq = (tid & 3) * 4;
    int brow = tid >> 4, bcol = (tid & 15) * 4;
    int ty = tid >> 4, tx = tid & 15;
    float acc[4][4];
#pragma unroll
    for (int r = 0; r < 4; ++r)
#pragma unroll
        for (int q = 0; q < 4; ++q) acc[r][q] = 0.f;
    for (int k0 = 0; k0 < K; k0 += 16) {
        float4 av = *reinterpret_cast<const float4*>(A + (size_t)(m0 + arow) * K + k0 + akq);
        float4 bv = make_float4(0, 0, 0, 0);
        if (n0 + bcol < N)
            bv = *reinterpret_cast<const float4*>(B + (size_t)(k0 + brow) * N + n0 + bcol);
        __syncthreads();
        As[(akq + 0) * 64 + arow] = av.x;
        As[(akq + 1) * 64 + arow] = av.y;
        As[(akq + 2) * 64 + arow] = av.z;
        As[(akq + 3) * 64 + arow] = av.w;
        *reinterpret_cast<float4*>(&Bs[brow * 64 + bcol]) = bv;
        __syncthreads();
#pragma unroll
        for (int kk = 0; kk < 16; ++kk) {
            float4 a4 = *reinterpret_cast<float4*>(&As[kk * 64 + ty * 4]);
            float4 b4 = *reinterpret_cast<float4*>(&Bs[kk * 64 + tx * 4]);
            float ar[4] = {a4.x, a4.y, a4.z, a4.w};
            float br[4] = {b4.x, b4.y, b4.z, b4.w};
#pragma unroll
            for (int r = 0; r < 4; ++r)
#pragma unroll
                for (int q = 0; q < 4; ++q)
                    acc[r][q] = fmaf(ar[r], br[q], acc[r][q]);
        }
    }
#pragma unroll
    for (int r = 0; r < 4; ++r) {
        int mm = m0 + ty * 4 + r;
#pragma unroll
        for (int q = 0; q < 4; ++q) {
            int nn = n0 + tx * 4 + q;
            if (nn < N) {
                float val = acc[r][q] + bias[nn];
                if (ACT == 0) val = fmaxf(val, 0.f);
                else val = 1.f / (1.f + expf(-val));
                C[(size_t)mm * N + nn] = val;
            }
        }
    }
}

extern "C" void kernel_launch(void* const* d_in, const int* in_sizes, int n_in,
                              void* d_out, int out_size, void* d_ws, size_t ws_size,
                              hipStream_t stream) {
    const float* x   = (const float*)d_in[0];
    const float* w1  = (const float*)d_in[1];
    const float* b1  = (const float*)d_in[2];
    const float* w2  = (const float*)d_in[3];
    const float* b2  = (const float*)d_in[4];
    const float* Wc  = (const float*)d_in[5];
    const float* d1w = (const float*)d_in[6];
    const float* d1b = (const float*)d_in[7];
    const float* d2w = (const float*)d_in[8];
    const float* d2b = (const float*)d_in[9];
    const float* d3w = (const float*)d_in[10];
    const float* d3b = (const float*)d_in[11];
    float* out = (float*)d_out;

    // ---- workspace (bytes): wB 21,233,664 | h1 209,715,200 | h2 18,874,368 = 249,823,232
    ushort* wBhi = (ushort*)d_ws;                          // 5,308,416 ushort
    ushort* wBlo = wBhi + 5308416;
    ushort* h1hi = (ushort*)((char*)d_ws + 21233664);      // 52,428,800 ushort
    ushort* h1lo = h1hi + 52428800;
    float*  h2   = (float*)((char*)d_ws + 230948864);      // 4,718,592 f

    // post-conv2 region aliases h1 (dead after conv2) -- write only after k_conv2m
    float* post = (float*)((char*)d_ws + 21233664);
    float* uT  = post + 4718592;         // 4,718,592
    float* bl  = post + 9437184;         // 5,898,240
    float* sT  = post + 15335424;        // 81,920
    float* Z   = post + 15417344;        // 5,120
    float* v   = post + 15422464;        // 81,920
    float* vT  = post + 15504384;        // 81,920
    float* dec = post + 15586304;        // 81,920
    float* r1  = post + 15668224;        // 262,144
    float* r2  = post + 15930368;        // 524,288

    int pred_off = out_size - 512;

    k_wt2<<<256, 256, 0, stream>>>(w2, wBhi, wBlo);
    k_conv1<<<2560, 256, 0, stream>>>(x, w1, b1, h1hi, h1lo);
    k_h2init<<<18432, 256, 0, stream>>>(b2, h2);
    k_conv2m<<<dim3(144, 2, 8), 256, 0, stream>>>(h1hi, h1lo, wBhi, wBlo, h2);
    // h1 is dead from here on; bl/sT/Z may now be zeroed (contiguous 5,985,280 f)
    k_zero4<<<5845, 256, 0, stream>>>(bl);
    k_squashT<<<dim3(1152, 2), 256, 0, stream>>>(h2, uT);

    for (int it = 0; it < 3; ++it) {
        k_s<<<dim3(144, 4), 256, 0, stream>>>(Wc, uT, bl, Z, sT, it == 0 ? 1 : 0);
        k_v<<<20, 256, 0, stream>>>(sT, v, vT, sT, Z);
        if (it < 2) k_bupd<<<dim3(144, 4), 256, 0, stream>>>(Wc, uT, vT, bl, Z);
    }

    k_pred<<<512, 256, 0, stream>>>(v, out, dec, pred_off);
    k_gemm<0><<<dim3(8, 8), 256, 0, stream>>>(dec, d1w, d1b, r1, 512, 160, 512);
    k_gemm<0><<<dim3(16, 8), 256, 0, stream>>>(r1, d2w, d2b, r2, 512, 512, 1024);
    k_gemm<1><<<dim3(13, 8), 256, 0, stream>>>(r2, d3w, d3b, out + 81920, 512, 1024, 784);
}

// Round 6
// 1419.152 us; speedup vs baseline: 1.1620x; 1.1620x over previous
//
#include <hip/hip_runtime.h>

#define CAPS_EPS 1e-8f

typedef __attribute__((ext_vector_type(8))) short short8;
typedef __attribute__((ext_vector_type(4))) float f32x4;

__device__ inline ushort bf16_rn(float f) {
    uint u = __float_as_uint(f);
    u += 0x7fff + ((u >> 16) & 1);
    return (ushort)(u >> 16);
}
__device__ inline float bf16_f(ushort h) { return __uint_as_float((uint)h << 16); }

// async global->LDS DMA, 16B per lane. LDS dst = wave-uniform base + lane*16.
__device__ __forceinline__ void gld16(const void* g, void* l) {
    __builtin_amdgcn_global_load_lds(
        (const __attribute__((address_space(1))) unsigned int*)g,
        (__attribute__((address_space(3))) unsigned int*)l, 16, 0, 0);
}

// ============================================================
// Layouts:
//   h1hi/h1lo [512][20][20][256] bf16 (NHWC) -- conv1 out, split
//   wBhi/wBlo [256][20736] bf16, k = (ky*9+kx)*256 + c
//   h2  [512*36][256] fp32
//   uT [9216][512]
//   bl  [1152*10][512], Z [10][512], sT [160][512], v [512][160], vT [160][512]
// NOTE: bl/uT/... alias h1 -- they may only be written AFTER conv2 consumed h1.
// ============================================================

// ---------- w2 [256][256*81] -> wB[n][t*256+c] hi/lo ----------
__global__ __launch_bounds__(256) void k_wt2(const float* __restrict__ w2,
                                             ushort* __restrict__ wBhi,
                                             ushort* __restrict__ wBlo) {
    int n = blockIdx.x;
    int c = threadIdx.x;
    const float* src = w2 + (size_t)n * 20736 + c * 81;
    ushort* dh = wBhi + (size_t)n * 20736 + c;
    ushort* dl = wBlo + (size_t)n * 20736 + c;
    for (int t = 0; t < 81; ++t) {
        float f = src[t];
        ushort hi = bf16_rn(f);
        ushort lo = bf16_rn(f - bf16_f(hi));
        dh[t * 256] = hi;
        dl[t * 256] = lo;
    }
}

// ---------- conv1 + relu -> bf16 split NHWC ----------
__global__ __launch_bounds__(256) void k_conv1(const float* __restrict__ x,
                                               const float* __restrict__ w1,
                                               const float* __restrict__ b1,
                                               ushort* __restrict__ h1hi,
                                               ushort* __restrict__ h1lo) {
    int blk = blockIdx.x;
    int b = blk / 5, strip = blk % 5;
    int y0 = strip * 4;
    int c = threadIdx.x;
    float w[81];
#pragma unroll
    for (int k = 0; k < 81; ++k) w[k] = w1[c * 81 + k];
    float bias = b1[c];
    const float* xb = x + (size_t)b * 784;
    for (int dy = 0; dy < 4; ++dy) {
        int y = y0 + dy;
        float acc[20];
#pragma unroll
        for (int i = 0; i < 20; ++i) acc[i] = bias;
#pragma unroll
        for (int ky = 0; ky < 9; ++ky) {
            float xr[28];
            const float4* xp = reinterpret_cast<const float4*>(xb + (y + ky) * 28);
#pragma unroll
            for (int q = 0; q < 7; ++q) {
                float4 v = xp[q];
                xr[q * 4 + 0] = v.x; xr[q * 4 + 1] = v.y;
                xr[q * 4 + 2] = v.z; xr[q * 4 + 3] = v.w;
            }
#pragma unroll
            for (int kx = 0; kx < 9; ++kx) {
                float wv = w[ky * 9 + kx];
#pragma unroll
                for (int xo = 0; xo < 20; ++xo)
                    acc[xo] = fmaf(xr[xo + kx], wv, acc[xo]);
            }
        }
#pragma unroll
        for (int xo = 0; xo < 20; ++xo) {
            float a = fmaxf(acc[xo], 0.f);
            ushort hi = bf16_rn(a);
            ushort lo = bf16_rn(a - bf16_f(hi));
            size_t o = ((size_t)(b * 20 + y) * 20 + xo) * 256 + c;
            h1hi[o] = hi;
            h1lo[o] = lo;
        }
    }
}

// ---------- h2 init with bias (runs BEFORE conv2; touches only h2) ----------
__global__ __launch_bounds__(256) void k_h2init(const float* __restrict__ b2,
                                                float* __restrict__ h2) {
    h2[(size_t)blockIdx.x * 256 + threadIdx.x] = b2[threadIdx.x];
}

// ---------- zero (float4 granularity; runs AFTER conv2 -- bl aliases h1) ----------
__global__ __launch_bounds__(256) void k_zero4(float* __restrict__ p) {
    reinterpret_cast<float4*>(p)[(size_t)blockIdx.x * 256 + threadIdx.x] = make_float4(0, 0, 0, 0);
}

// ---------- conv2: split-bf16 MFMA implicit GEMM, global_load_lds staging ----------
// C[18432][256] += A(im2col h1) * B.  Tile 128m x 256n (FULL N), BK=32, K-split 8.
// Each im2col A byte is DMA'd exactly once (no n-tile re-fetch).
// 3-term split: hi*hi + hi*lo + lo*hi.  LDS unpadded (DMA is lane-linear).
__global__ __launch_bounds__(256, 2) void k_conv2m(const ushort* __restrict__ h1hi,
                                                   const ushort* __restrict__ h1lo,
                                                   const ushort* __restrict__ wBhi,
                                                   const ushort* __restrict__ wBlo,
                                                   float* __restrict__ h2) {
    __shared__ ushort Ahi[128 * 32];   // 8 KB
    __shared__ ushort Alo[128 * 32];
    __shared__ ushort Bhi[256 * 32];   // 16 KB
    __shared__ ushort Blo[256 * 32];
    int tid = threadIdx.x;
    int m0 = blockIdx.x * 128;
    int kbase = blockIdx.y * 2592;          // 20736 / 8

    int wv = tid >> 6, lane = tid & 63;
    int cq = (lane & 3) * 8;                // 16B chunk within a 64B row

    // ---- A DMA: wave wv stages rows [32wv, 32wv+32); 2 instrs of 16 rows each.
    int ra = wv * 32 + (lane >> 2);
    int mA0 = m0 + ra, mA1 = mA0 + 16;
    int mb0 = mA0 / 36, mp0 = mA0 - mb0 * 36;
    int mb1 = mA1 / 36, mp1 = mA1 - mb1 * 36;
    size_t a0 = ((size_t)mb0 * 400 + (mp0 / 6) * 40 + (mp0 % 6) * 2) * 256 + cq;
    size_t a1 = ((size_t)mb1 * 400 + (mp1 / 6) * 40 + (mp1 % 6) * 2) * 256 + cq;
    int ldsA = wv * 1024;                   // ushort offset; instr1 at +512

    // ---- B DMA: wave wv stages rows [64wv, 64wv+64); 4 instrs of 16 rows each.
    int rb = wv * 64 + (lane >> 2);
    size_t bB = (size_t)rb * 20736 + cq;    // instr q adds q*16*20736
    int ldsB = wv * 2048;                   // instr q at +q*512

    // ---- frag mapping: wave covers 64m x 128n quadrant
    int mhalf = (wv >> 1) * 64, nhalf = (wv & 1) * 128;
    int lrow = lane & 15, quad = lane >> 4;

    f32x4 acc[4][8];
#pragma unroll
    for (int a = 0; a < 4; ++a)
#pragma unroll
        for (int bq = 0; bq < 8; ++bq) acc[a][bq] = (f32x4){0.f, 0.f, 0.f, 0.f};

    for (int ks = 0; ks < 81; ++ks) {
        int k = kbase + ks * 32;
        int t = k >> 8, cc = k & 255;
        int ky = t / 9, kx = t - ky * 9;
        size_t koffA = (size_t)(ky * 5120 + kx * 256 + cc);

        __syncthreads();                    // prev iter's reads done
        gld16(h1hi + a0 + koffA, &Ahi[ldsA]);
        gld16(h1hi + a1 + koffA, &Ahi[ldsA + 512]);
        gld16(h1lo + a0 + koffA, &Alo[ldsA]);
        gld16(h1lo + a1 + koffA, &Alo[ldsA + 512]);
#pragma unroll
        for (int q = 0; q < 4; ++q) {
            size_t bo = bB + (size_t)q * 331776 + k;   // q*16*20736
            gld16(wBhi + bo, &Bhi[ldsB + q * 512]);
            gld16(wBlo + bo, &Blo[ldsB + q * 512]);
        }
        __syncthreads();                    // vmcnt(0) drain -> LDS ready

        // preload all A fragments (64 ushort regs)
        short8 ah[4], al[4];
#pragma unroll
        for (int tm = 0; tm < 4; ++tm) {
            int off = (mhalf + tm * 16 + lrow) * 32 + quad * 8;
            ah[tm] = *reinterpret_cast<short8*>(&Ahi[off]);
            al[tm] = *reinterpret_cast<short8*>(&Alo[off]);
        }
#pragma unroll
        for (int tn = 0; tn < 8; ++tn) {
            int off = (nhalf + tn * 16 + lrow) * 32 + quad * 8;
            short8 bh = *reinterpret_cast<short8*>(&Bhi[off]);
            short8 bl2 = *reinterpret_cast<short8*>(&Blo[off]);
#pragma unroll
            for (int tm = 0; tm < 4; ++tm) {
                acc[tm][tn] = __builtin_amdgcn_mfma_f32_16x16x32_bf16(ah[tm], bh, acc[tm][tn], 0, 0, 0);
                acc[tm][tn] = __builtin_amdgcn_mfma_f32_16x16x32_bf16(ah[tm], bl2, acc[tm][tn], 0, 0, 0);
                acc[tm][tn] = __builtin_amdgcn_mfma_f32_16x16x32_bf16(al[tm], bh, acc[tm][tn], 0, 0, 0);
            }
        }
    }

#pragma unroll
    for (int tm = 0; tm < 4; ++tm) {
        int mrow = m0 + mhalf + tm * 16 + quad * 4;
#pragma unroll
        for (int tn = 0; tn < 8; ++tn) {
            int ncol = nhalf + tn * 16 + lrow;
#pragma unroll
            for (int r = 0; r < 4; ++r)
                atomicAdd(&h2[(size_t)(mrow + r) * 256 + ncol], acc[tm][tn][r]);
        }
    }
}

// ---------- fused squash + transpose: h2 -> uT[(i*8+n)][b] ----------
__global__ __launch_bounds__(256) void k_squashT(const float* __restrict__ h2,
                                                 float* __restrict__ uT) {
    int i = blockIdx.x;                       // 0..1151
    int b = blockIdx.y * 256 + threadIdx.x;   // 0..511
    int g = i / 36, s = i - g * 36;
    const float* hp = h2 + ((size_t)b * 36 + s) * 256 + g;
    float val[8];
    float s2 = 0.f;
#pragma unroll
    for (int n = 0; n < 8; ++n) {
        val[n] = hp[n * 32];
        s2 = fmaf(val[n], val[n], s2);
    }
    float scale = s2 / ((1.f + s2) * sqrtf(s2 + CAPS_EPS));
#pragma unroll
    for (int n = 0; n < 8; ++n)
        uT[((size_t)i * 8 + n) * 512 + b] = val[n] * scale;
}

// ---------- s[b,j,m] = sum_i c * (W u), c from exp(bl)/Z (or uniform it0) ----------
__global__ __launch_bounds__(256) void k_s(const float* __restrict__ Wc,
                                           const float* __restrict__ uT,
                                           const float* __restrict__ bl,
                                           const float* __restrict__ Z,
                                           float* __restrict__ sT,
                                           int first) {
    __shared__ float lw[8 * 1280];
    int tid = threadIdx.x;
    int i0 = blockIdx.x * 8;
    int b = blockIdx.y * 128 + (tid & 127);
    int mh = tid >> 7;
    const float* wg = Wc + (size_t)i0 * 1280;
#pragma unroll
    for (int r = 0; r < 10; ++r) {
        int q4 = (r * 256 + tid) * 4;
        *reinterpret_cast<float4*>(&lw[q4]) = *reinterpret_cast<const float4*>(wg + q4);
    }
    __syncthreads();
    float rzs[10];
    if (!first) {
#pragma unroll
        for (int j = 0; j < 10; ++j) rzs[j] = 1.0f / Z[j * 512 + b];
    }
    float acc[80];
#pragma unroll
    for (int q = 0; q < 80; ++q) acc[q] = 0.f;
    for (int di = 0; di < 8; ++di) {
        int i = i0 + di;
        float ur[8];
#pragma unroll
        for (int n = 0; n < 8; ++n) ur[n] = uT[((size_t)i * 8 + n) * 512 + b];
#pragma unroll
        for (int j = 0; j < 10; ++j) {
            float c;
            if (first) c = (1.0f / 1152.0f);
            else c = expf(bl[((size_t)i * 10 + j) * 512 + b]) * rzs[j];
            const float* wp = &lw[((di * 10 + j) * 8) * 16 + mh * 8];
#pragma unroll
            for (int mm = 0; mm < 8; ++mm) {
                float uh = 0.f;
#pragma unroll
                for (int n = 0; n < 8; ++n) uh = fmaf(wp[n * 16 + mm], ur[n], uh);
                acc[j * 8 + mm] = fmaf(c, uh, acc[j * 8 + mm]);
            }
        }
    }
#pragma unroll
    for (int j = 0; j < 10; ++j)
#pragma unroll
        for (int mm = 0; mm < 8; ++mm)
            atomicAdd(&sT[(j * 16 + mh * 8 + mm) * 512 + b], acc[j * 8 + mm]);
}

// ---------- v = squash(s); write v, vT; zero sT and Z for next round ----------
__global__ __launch_bounds__(256) void k_v(const float* __restrict__ sT,
                                           float* __restrict__ v,
                                           float* __restrict__ vT,
                                           float* __restrict__ sTz,
                                           float* __restrict__ Z) {
    int idx = blockIdx.x * 256 + threadIdx.x;   // 5120
    int j = idx >> 9;
    int b = idx & 511;
    float sv[16];
    float s2 = 0.f;
#pragma unroll
    for (int m = 0; m < 16; ++m) {
        sv[m] = sT[(j * 16 + m) * 512 + b];
        s2 = fmaf(sv[m], sv[m], s2);
    }
    float scale = s2 / ((1.f + s2) * sqrtf(s2 + CAPS_EPS));
#pragma unroll
    for (int m = 0; m < 16; ++m) {
        float val = sv[m] * scale;
        v[(size_t)b * 160 + j * 16 + m] = val;
        vT[(j * 16 + m) * 512 + b] = val;
        sTz[(j * 16 + m) * 512 + b] = 0.f;
    }
    Z[idx] = 0.f;
}

// ---------- b_log += u . (W v); accumulate Z = sum_i exp(b_log_new) ----------
__global__ __launch_bounds__(256) void k_bupd(const float* __restrict__ Wc,
                                              const float* __restrict__ uT,
                                              const float* __restrict__ vT,
                                              float* __restrict__ bl,
                                              float* __restrict__ Z) {
    __shared__ float lw[8 * 1280];
    int tid = threadIdx.x;
    int i0 = blockIdx.x * 8;
    int b = blockIdx.y * 128 + (tid & 127);
    int ih = tid >> 7;
    const float* wg = Wc + (size_t)i0 * 1280;
#pragma unroll
    for (int r = 0; r < 10; ++r) {
        int q4 = (r * 256 + tid) * 4;
        *reinterpret_cast<float4*>(&lw[q4]) = *reinterpret_cast<const float4*>(wg + q4);
    }
    __syncthreads();
    float ur[4][8];
#pragma unroll
    for (int ii = 0; ii < 4; ++ii) {
        int i = i0 + ih * 4 + ii;
#pragma unroll
        for (int n = 0; n < 8; ++n) ur[ii][n] = uT[((size_t)i * 8 + n) * 512 + b];
    }
    for (int j = 0; j < 10; ++j) {
        float vj[16];
#pragma unroll
        for (int m = 0; m < 16; ++m) vj[m] = vT[(j * 16 + m) * 512 + b];
        float zp = 0.f;
#pragma unroll
        for (int ii = 0; ii < 4; ++ii) {
            int di = ih * 4 + ii;
            const float* wp = &lw[((di * 10 + j) * 8) * 16];
            float t = 0.f;
#pragma unroll
            for (int n = 0; n < 8; ++n) {
                float wvv = 0.f;
#pragma unroll
                for (int m = 0; m < 16; ++m) wvv = fmaf(wp[n * 16 + m], vj[m], wvv);
                t = fmaf(ur[ii][n], wvv, t);
            }
            size_t idx = ((size_t)(i0 + di) * 10 + j) * 512 + b;
            float nb = bl[idx] + t;
            bl[idx] = nb;
            zp += expf(nb);
        }
        atomicAdd(&Z[j * 512 + b], zp);
    }
}

// ---------- caps->out, pred->out, masked dec_in ----------
__global__ __launch_bounds__(256) void k_pred(const float* __restrict__ v,
                                              float* __restrict__ out,
                                              float* __restrict__ dec,
                                              int pred_off) {
    int b = blockIdx.x, t = threadIdx.x;
    __shared__ float sq[160];
    __shared__ float nrm[10];
    __shared__ int ip;
    float val = 0.f;
    if (t < 160) {
        val = v[(size_t)b * 160 + t];
        out[(size_t)b * 160 + t] = val;
        sq[t] = val * val;
    }
    __syncthreads();
    if (t < 10) {
        float s = 0.f;
#pragma unroll
        for (int k = 0; k < 16; ++k) s += sq[t * 16 + k];
        nrm[t] = s;
    }
    __syncthreads();
    if (t == 0) {
        float best = nrm[0];
        int bi = 0;
        for (int j = 1; j < 10; ++j)
            if (nrm[j] > best) { best = nrm[j]; bi = j; }
        ip = bi;
        out[(size_t)pred_off + b] = (float)bi;
    }
    __syncthreads();
    if (t < 160) dec[(size_t)b * 160 + t] = ((t >> 4) == ip) ? val : 0.f;
}

// ---------- decoder GEMM ----------
template <int ACT>
__global__ __launch_bounds__(256) void k_gemm(const float* __restrict__ A,
                                              const float* __restrict__ B,
                                              const float* __restrict__ bias,
                                              float* __restrict__ C,
                                              int M, int K, int N) {
    __shared__ float As[16 * 64];
    __shared__ float Bs[16 * 64];
    int tid = threadIdx.x;
    int m0 = blockIdx.y * 64, n0 = blockIdx.x * 64;
    int arow = tid >> 2, akq = (tid & 3) * 4;
    int brow = tid >> 4, bcol = (tid & 15) * 4;
    int ty = tid >> 4, tx = tid & 15;
    float acc[4][4];
#pragma unroll
    for (int r = 0; r < 4; ++r)
#pragma unroll
        for (int q = 0; q < 4; ++q) acc[r][q] = 0.f;
    for (int k0 = 0; k0 < K; k0 += 16) {
        float4 av = *reinterpret_cast<const float4*>(A + (size_t)(m0 + arow) * K + k0 + akq);
        float4 bv = make_float4(0, 0, 0, 0);
        if (n0 + bcol < N)
            bv = *reinterpret_cast<const float4*>(B + (size_t)(k0 + brow) * N + n0 + bcol);
        __syncthreads();
        As[(akq + 0) * 64 + arow] = av.x;
        As[(akq + 1) * 64 + arow] = av.y;
        As[(akq + 2) * 64 + arow] = av.z;
        As[(akq + 3) * 64 + arow] = av.w;
        *reinterpret_cast<float4*>(&Bs[brow * 64 + bcol]) = bv;
        __syncthreads();
#pragma unroll
        for (int kk = 0; kk < 16; ++kk) {
            float4 a4 = *reinterpret_cast<float4*>(&As[kk * 64 + ty * 4]);
            float4 b4 = *reinterpret_cast<float4*>(&Bs[kk * 64 + tx * 4]);
            float ar[4] = {a4.x, a4.y, a4.z, a4.w};
            float br[4] = {b4.x, b4.y, b4.z, b4.w};
#pragma unroll
            for (int r = 0; r < 4; ++r)
#pragma unroll
                for (int q = 0; q < 4; ++q)
                    acc[r][q] = fmaf(ar[r], br[q], acc[r][q]);
        }
    }
#pragma unroll
    for (int r = 0; r < 4; ++r) {
        int mm = m0 + ty * 4 + r;
#pragma unroll
        for (int q = 0; q < 4; ++q) {
            int nn = n0 + tx * 4 + q;
            if (nn < N) {
                float val = acc[r][q] + bias[nn];
                if (ACT == 0) val = fmaxf(val, 0.f);
                else val = 1.f / (1.f + expf(-val));
                C[(size_t)mm * N + nn] = val;
            }
        }
    }
}

extern "C" void kernel_launch(void* const* d_in, const int* in_sizes, int n_in,
                              void* d_out, int out_size, void* d_ws, size_t ws_size,
                              hipStream_t stream) {
    const float* x   = (const float*)d_in[0];
    const float* w1  = (const float*)d_in[1];
    const float* b1  = (const float*)d_in[2];
    const float* w2  = (const float*)d_in[3];
    const float* b2  = (const float*)d_in[4];
    const float* Wc  = (const float*)d_in[5];
    const float* d1w = (const float*)d_in[6];
    const float* d1b = (const float*)d_in[7];
    const float* d2w = (const float*)d_in[8];
    const float* d2b = (const float*)d_in[9];
    const float* d3w = (const float*)d_in[10];
    const float* d3b = (const float*)d_in[11];
    float* out = (float*)d_out;

    // ---- workspace (bytes): wB 21,233,664 | h1 209,715,200 | h2 18,874,368 = 249,823,232
    ushort* wBhi = (ushort*)d_ws;                          // 5,308,416 ushort
    ushort* wBlo = wBhi + 5308416;
    ushort* h1hi = (ushort*)((char*)d_ws + 21233664);      // 52,428,800 ushort
    ushort* h1lo = h1hi + 52428800;
    float*  h2   = (float*)((char*)d_ws + 230948864);      // 4,718,592 f

    // post-conv2 region aliases h1 (dead after conv2) -- write only after k_conv2m
    float* post = (float*)((char*)d_ws + 21233664);
    float* uT  = post + 4718592;         // 4,718,592
    float* bl  = post + 9437184;         // 5,898,240
    float* sT  = post + 15335424;        // 81,920
    float* Z   = post + 15417344;        // 5,120
    float* v   = post + 15422464;        // 81,920
    float* vT  = post + 15504384;        // 81,920
    float* dec = post + 15586304;        // 81,920
    float* r1  = post + 15668224;        // 262,144
    float* r2  = post + 15930368;        // 524,288

    int pred_off = out_size - 512;

    k_wt2<<<256, 256, 0, stream>>>(w2, wBhi, wBlo);
    k_conv1<<<2560, 256, 0, stream>>>(x, w1, b1, h1hi, h1lo);
    k_h2init<<<18432, 256, 0, stream>>>(b2, h2);
    k_conv2m<<<dim3(144, 8), 256, 0, stream>>>(h1hi, h1lo, wBhi, wBlo, h2);
    // h1 is dead from here on; bl/sT/Z may now be zeroed (contiguous 5,985,280 f)
    k_zero4<<<5845, 256, 0, stream>>>(bl);
    k_squashT<<<dim3(1152, 2), 256, 0, stream>>>(h2, uT);

    for (int it = 0; it < 3; ++it) {
        k_s<<<dim3(144, 4), 256, 0, stream>>>(Wc, uT, bl, Z, sT, it == 0 ? 1 : 0);
        k_v<<<20, 256, 0, stream>>>(sT, v, vT, sT, Z);
        if (it < 2) k_bupd<<<dim3(144, 4), 256, 0, stream>>>(Wc, uT, vT, bl, Z);
    }

    k_pred<<<512, 256, 0, stream>>>(v, out, dec, pred_off);
    k_gemm<0><<<dim3(8, 8), 256, 0, stream>>>(dec, d1w, d1b, r1, 512, 160, 512);
    k_gemm<0><<<dim3(16, 8), 256, 0, stream>>>(r1, d2w, d2b, r2, 512, 512, 1024);
    k_gemm<1><<<dim3(13, 8), 256, 0, stream>>>(r2, d3w, d3b, out + 81920, 512, 1024, 784);
}